// Round 10
// baseline (298.653 us; speedup 1.0000x reference)
//
#include <hip/hip_runtime.h>
#include <math.h>

#define PP 3072
#define NB 15
#define NM 8
#define XG 24     // x-groups of 128 per object
#define NCH 3     // y-chunks of 1024

typedef _Float16 hv2 __attribute__((ext_vector_type(2)));

static __device__ __forceinline__ unsigned h2u(hv2 h) {
  return __builtin_bit_cast(unsigned, h);
}
static __device__ __forceinline__ hv2 u2h(unsigned u) {
  return __builtin_bit_cast(hv2, u);
}
static __device__ __forceinline__ hv2 hmin2(hv2 a, hv2 b) {
  return __builtin_elementwise_min(a, b);
}
static __device__ __forceinline__ unsigned pkf16(float lo, float hi) {
  hv2 h;
  h.x = (_Float16)lo;
  h.y = (_Float16)hi;
  return h2u(h);
}

// ws layout (bytes):
//  sums:  [0,480)               float[15*8]
//  cntf:  [480,960)             float[15*8]
//  bits:  [1024,47104)          u8 [15][3072]   mask byte per point
//  sidx:  [47104,139264)        u16[15][3072]   sorted-by-byte point order
//  runpk: [139264,154624)       u32[15][256]    (run_end<<8)|run_byte
//  segf:  [154624,154984)       u8 [15][24]     first run idx per 128-y segment
//  xt:    [155648,708608)       u32[15*3072*3]  pk(pred,gt) coords, x order
//  yts:   [708608,1261568)      u32[15*3072*3]  pk(gt,pred) coords, sorted order
//  plane: [1261568,4210688)     u32[15][8][2][3072] f32-bits min d^2
#define WS_SUMS 0
#define WS_CNTF 480
#define WS_BITS 1024
#define WS_SIDX 47104
#define WS_RUNPK 139264
#define WS_SEGF 154624
#define WS_XT 155648
#define WS_YTS 708608
#define WS_PLANE 1261568

__global__ __launch_bounds__(1024) void sort_kernel(
    const void* __restrict__ mask, unsigned char* __restrict__ bits,
    unsigned short* __restrict__ sidx, unsigned* __restrict__ runpk,
    unsigned char* __restrict__ segf) {
  const int b = blockIdx.x;
  const int tid = threadIdx.x;
  __shared__ int hist[256];
  __shared__ int scanbuf[256];
  __shared__ int pfx[257];
  __shared__ int rankbuf[256];
  __shared__ int cnt[256];
  if (tid < 256) { hist[tid] = 0; cnt[tid] = 0; }

  // mask element-width probe (bool bytes vs int32 0/1)
  const uint4* pw = (const uint4*)mask;
  uint4 w0 = pw[0], w1 = pw[1], w2 = pw[2], w3 = pw[3];
  unsigned acc = (w0.x | w0.y | w0.z | w0.w | w1.x | w1.y | w1.z | w1.w |
                  w2.x | w2.y | w2.z | w2.w | w3.x | w3.y | w3.z | w3.w) &
                 0xFFFFFF00u;
  const bool bytemode = (acc != 0);
  const unsigned char* mb = (const unsigned char*)mask;
  const int* mi = (const int*)mask;

  unsigned char mybyte[3];
  __syncthreads();
#pragma unroll
  for (int k = 0; k < 3; k++) {
    int p = k * 1024 + tid;
    unsigned v = 0;
#pragma unroll
    for (int m = 0; m < NM; m++) {
      long q = (long)(b * NM + m) * PP + p;
      unsigned bit = bytemode ? (mb[q] != 0) : (mi[q] != 0);
      v |= bit << m;
    }
    mybyte[k] = (unsigned char)v;
    bits[b * PP + p] = (unsigned char)v;
    atomicAdd(&hist[v], 1);
  }
  __syncthreads();

  // inclusive scans: hist -> pfx, (hist>0) -> rankbuf
  if (tid < 256) { scanbuf[tid] = hist[tid]; rankbuf[tid] = hist[tid] > 0; }
  __syncthreads();
  for (int off = 1; off < 256; off <<= 1) {
    int v = 0, u = 0;
    if (tid < 256 && tid >= off) { v = scanbuf[tid - off]; u = rankbuf[tid - off]; }
    __syncthreads();
    if (tid < 256 && tid >= off) { scanbuf[tid] += v; rankbuf[tid] += u; }
    __syncthreads();
  }
  if (tid == 0) pfx[0] = 0;
  if (tid < 256) pfx[tid + 1] = scanbuf[tid];
  __syncthreads();

  if (tid < 256 && hist[tid] > 0) {
    int rk = rankbuf[tid] - 1;
    runpk[b * 256 + rk] = ((unsigned)pfx[tid + 1] << 8) | (unsigned)tid;
  }
  if (tid < 24) {
    int ys = tid * 128, c = 0;
    for (int v = 0; v < 256; v++)
      c += (hist[v] > 0 && pfx[v + 1] <= ys) ? 1 : 0;
    segf[b * 24 + tid] = (unsigned char)c;
  }
#pragma unroll
  for (int k = 0; k < 3; k++) {
    int p = k * 1024 + tid;
    unsigned v = mybyte[k];
    int rank = pfx[v] + atomicAdd(&cnt[v], 1);
    sidx[b * PP + rank] = (unsigned short)p;
  }
}

__global__ __launch_bounds__(256) void pack_kernel(
    const float* __restrict__ pred, const float* __restrict__ gt,
    const unsigned short* __restrict__ sidx, unsigned* __restrict__ xt,
    unsigned* __restrict__ yts, unsigned* __restrict__ plane,
    float* __restrict__ sums, float* __restrict__ cntf) {
  const int i = blockIdx.x * 256 + threadIdx.x;  // grid = exactly NB*PP = 46080
  if (blockIdx.x == 0 && threadIdx.x < 240) {
    if (threadIdx.x < 120) sums[threadIdx.x] = 0.f;
    else cntf[threadIdx.x - 120] = 0.f;
  }
  // init plane to +inf (f32 bits): 737280 entries = 46080 threads * 16
#pragma unroll
  for (int k = 0; k < 16; k++) plane[k * 46080 + i] = 0x7F800000u;

  const int b = i / PP;
  const long g = i;
  xt[g * 3 + 0] = pkf16(pred[g * 3 + 0], gt[g * 3 + 0]);  // lo=pred_x, hi=gt_x
  xt[g * 3 + 1] = pkf16(pred[g * 3 + 1], gt[g * 3 + 1]);
  xt[g * 3 + 2] = pkf16(pred[g * 3 + 2], gt[g * 3 + 2]);
  const long p2 = (long)b * PP + sidx[i];
  yts[g * 3 + 0] = pkf16(gt[p2 * 3 + 0], pred[p2 * 3 + 0]);  // lo=gt_y, hi=pred_y
  yts[g * 3 + 1] = pkf16(gt[p2 * 3 + 1], pred[p2 * 3 + 1]);
  yts[g * 3 + 2] = pkf16(gt[p2 * 3 + 2], pred[p2 * 3 + 2]);
}

__global__ __launch_bounds__(512, 8) void chamfer_main(
    const unsigned* __restrict__ xt, const unsigned* __restrict__ yts,
    const unsigned* __restrict__ runpk, const unsigned char* __restrict__ segf,
    unsigned* __restrict__ plane) {
  const int xg = blockIdx.x, b = blockIdx.y, ch = blockIdx.z;
  const int tid = threadIdx.x, lane = tid & 63, w = tid >> 6;

  __shared__ unsigned ytile[1024 * 3];  // 12 KB, this chunk's sorted y coords
  __shared__ unsigned runl[256];        // 1 KB run table

  const unsigned* src = yts + ((long)b * PP + ch * 1024) * 3;
  for (int i = tid; i < 1024 * 3; i += 512) ytile[i] = src[i];
  if (tid < 256) runl[tid] = runpk[b * 256 + tid];

  const long xbase = (long)b * PP + xg * 128;
  const unsigned* xp0 = xt + (xbase + lane) * 3;
  const unsigned* xp1 = xt + (xbase + 64 + lane) * 3;
  const hv2 x0x = u2h(xp0[0]), x0y = u2h(xp0[1]), x0z = u2h(xp0[2]);
  const hv2 x1x = u2h(xp1[0]), x1y = u2h(xp1[1]), x1z = u2h(xp1[2]);
  __syncthreads();

  int j = ch * 1024 + w * 128;
  const int ye = j + 128;
  int r = __builtin_amdgcn_readfirstlane((int)segf[b * 24 + ch * 8 + w]);
  unsigned pk = __builtin_amdgcn_readfirstlane(runl[r]);
  unsigned* const pl = plane + (long)b * NM * 2 * PP + xg * 128 + lane;

  while (j < ye) {
    const int rn = r + 1 < 255 ? r + 1 : 255;
    const unsigned pkn = runl[rn];  // prefetch next run entry
    const int e = (int)(pk >> 8);
    const unsigned byte = pk & 255u;
    const int e2 = e < ye ? e : ye;
    hv2 dmin0 = u2h(0x7C007C00u), dmin1 = u2h(0x7C007C00u);
    // pure inner loop: 3 LDS words + 12 pk ops for 4 (x,dir) pairs, no merge
    for (; j < e2; j++) {
      const int lj = (j - ch * 1024) * 3;
      const hv2 qx = u2h(ytile[lj]), qy = u2h(ytile[lj + 1]), qz = u2h(ytile[lj + 2]);
      hv2 s = x0x - qx;
      hv2 d0 = s * s;
      s = x0y - qy;
      d0 += s * s;
      s = x0z - qz;
      d0 += s * s;
      s = x1x - qx;
      hv2 d1 = s * s;
      s = x1y - qy;
      d1 += s * s;
      s = x1z - qz;
      d1 += s * s;
      dmin0 = hmin2(dmin0, d0);
      dmin1 = hmin2(dmin1, d1);
    }
    // run-boundary merge: fire-and-forget global atomicMin (side effect ->
    // cannot be speculated/if-converted/flattened into the inner loop)
    const unsigned u00 = __float_as_uint((float)dmin0.x);
    const unsigned u01 = __float_as_uint((float)dmin0.y);
    const unsigned u10 = __float_as_uint((float)dmin1.x);
    const unsigned u11 = __float_as_uint((float)dmin1.y);
#pragma unroll
    for (int m = 0; m < NM; m++)
      if ((byte >> m) & 1) {
        unsigned* p0 = pl + (long)(m * 2) * PP;
        atomicMin(p0, u00);
        atomicMin(p0 + 64, u10);
        atomicMin(p0 + PP, u01);
        atomicMin(p0 + PP + 64, u11);
      }
    pk = __builtin_amdgcn_readfirstlane(pkn);
    r++;
  }
}

__global__ __launch_bounds__(128) void obj_partial(
    const unsigned char* __restrict__ bits, const unsigned* __restrict__ plane,
    float* __restrict__ sums, float* __restrict__ cntf) {
  const int b = blockIdx.x, xg = blockIdx.y;
  const int tid = threadIdx.x, lane = tid & 63, wv = tid >> 6;
  const int x = xg * 128 + tid;
  const unsigned byte = bits[(long)b * PP + x];
  __shared__ float red[2][NM][2];
#pragma unroll
  for (int m = 0; m < NM; m++) {
    const long o = (long)((b * NM + m) * 2) * PP + x;
    const float f0 = __uint_as_float(plane[o]);
    const float f1 = __uint_as_float(plane[o + PP]);
    const int bit = (byte >> m) & 1;
    float val = bit ? (sqrtf(f0) + sqrtf(f1)) : 0.f;
    float c = (float)bit;
    for (int off = 32; off > 0; off >>= 1) {
      val += __shfl_down(val, off);
      c += __shfl_down(c, off);
    }
    if (lane == 0) { red[wv][m][0] = val; red[wv][m][1] = c; }
  }
  __syncthreads();
  if (tid < NM) {
    atomicAdd(&sums[b * NM + tid], red[0][tid][0] + red[1][tid][0]);
    atomicAdd(&cntf[b * NM + tid], red[0][tid][1] + red[1][tid][1]);
  }
}

__global__ void scalar_kernel(const float* __restrict__ sums,
                              const float* __restrict__ cntf,
                              float* __restrict__ out) {
  const int lane = threadIdx.x;
  float o = 0.f;
  int c = 0;
  if (lane < NB) {
    float objsum = 0.f;
    int nvalid = 0;
#pragma unroll
    for (int m = 0; m < NM; m++) {
      int n = (int)(cntf[lane * NM + m] + 0.5f);
      if (n >= 2) {
        nvalid++;
        objsum += 0.5f * sums[lane * NM + m] / (float)n;
      }
    }
    if (nvalid > 0) { o = objsum / (float)nvalid; c = 1; }
  }
  for (int off = 32; off > 0; off >>= 1) {
    o += __shfl_down(o, off);
    c += __shfl_down(c, off);
  }
  if (lane == 0) out[0] = c > 0 ? o / (float)c : 0.f;
}

extern "C" void kernel_launch(void* const* d_in, const int* in_sizes, int n_in,
                              void* d_out, int out_size, void* d_ws, size_t ws_size,
                              hipStream_t stream) {
  const float* pred = (const float*)d_in[0];
  const float* gt = (const float*)d_in[1];
  const void* mask = d_in[3];

  char* ws = (char*)d_ws;
  float* sums = (float*)(ws + WS_SUMS);
  float* cntf = (float*)(ws + WS_CNTF);
  unsigned char* bits = (unsigned char*)(ws + WS_BITS);
  unsigned short* sidx = (unsigned short*)(ws + WS_SIDX);
  unsigned* runpk = (unsigned*)(ws + WS_RUNPK);
  unsigned char* segf = (unsigned char*)(ws + WS_SEGF);
  unsigned* xt = (unsigned*)(ws + WS_XT);
  unsigned* yts = (unsigned*)(ws + WS_YTS);
  unsigned* plane = (unsigned*)(ws + WS_PLANE);
  float* out = (float*)d_out;

  sort_kernel<<<NB, 1024, 0, stream>>>(mask, bits, sidx, runpk, segf);
  pack_kernel<<<NB * PP / 256, 256, 0, stream>>>(pred, gt, sidx, xt, yts, plane,
                                                 sums, cntf);
  chamfer_main<<<dim3(XG, NB, NCH), 512, 0, stream>>>(xt, yts, runpk, segf, plane);
  obj_partial<<<dim3(NB, XG), 128, 0, stream>>>(bits, plane, sums, cntf);
  scalar_kernel<<<1, 64, 0, stream>>>(sums, cntf, out);
}